// Round 1
// baseline (240.632 us; speedup 1.0000x reference)
//
#include <hip/hip_runtime.h>
#include <stdint.h>

typedef short bf8v __attribute__((ext_vector_type(8)));
typedef float f4v  __attribute__((ext_vector_type(4)));
typedef short s8v  __attribute__((ext_vector_type(8)));

__device__ __forceinline__ float bf2f(short b){
  unsigned u = ((unsigned)(unsigned short)b) << 16;
  union { unsigned u; float f; } c; c.u = u; return c.f;
}
__device__ __forceinline__ short f2bf(float f){
  union { float f; unsigned u; } c; c.f = f;
  unsigned r = (c.u + 0x7FFFu + ((c.u >> 16) & 1u)) >> 16;
  return (short)r;
}
__device__ __forceinline__ void gload16(const short* g, short* l){
  __builtin_amdgcn_global_load_lds(
      (const __attribute__((address_space(1))) void*)g,
      (__attribute__((address_space(3))) void*)l, 16, 0, 0);
}

// ---------------- prep: lengths -> offsets (int32/int64 autodetect) ----------
__global__ void prep_kernel(const int* lx, const int* lm, int* meta){
  if (threadIdx.x != 0) return;
  int is64 = ((lx[1] | lx[3] | lx[5] | lx[7]) == 0) ? 1 : 0;
  int ox = 0, om = 0;
  for (int b = 0; b < 8; ++b){
    int a = is64 ? lx[2*b] : lx[b];
    int c = is64 ? lm[2*b] : lm[b];
    meta[b] = a; meta[8+b] = c;
    meta[16+b] = ox; meta[25+b] = om;
    ox += a; om += c;
  }
  meta[24] = ox; meta[33] = om;
}

// ---------------- f32 -> bf16 conversion for x and mem -----------------------
__global__ __launch_bounds__(256) void cvt2bf(const float* __restrict__ x,
                                              const float* __restrict__ mem,
                                              short* __restrict__ xb,
                                              short* __restrict__ mb,
                                              long long n){
  long long t = (long long)blockIdx.x * 256 + threadIdx.x;
  long long i = t * 8;
  const float* s; short* d;
  if (i < n){ s = x + i; d = xb + i; }
  else {
    i -= n; if (i >= n) return;
    s = mem + i; d = mb + i;
  }
  float4 f0 = *(const float4*)s;
  float4 f1 = *(const float4*)(s + 4);
  s8v o;
  o[0]=f2bf(f0.x); o[1]=f2bf(f0.y); o[2]=f2bf(f0.z); o[3]=f2bf(f0.w);
  o[4]=f2bf(f1.x); o[5]=f2bf(f1.y); o[6]=f2bf(f1.z); o[7]=f2bf(f1.w);
  *(s8v*)d = o;
}

// ---------------- weight transpose + convert: W[K][N] -> WT[N][K] bf16 -------
__global__ __launch_bounds__(256) void cvt_w_t(
    const float* __restrict__ Wq, const float* __restrict__ Wk,
    const float* __restrict__ Wv, const float* __restrict__ Wo,
    const float* __restrict__ W1, const float* __restrict__ W2,
    short* __restrict__ WqT, short* __restrict__ WkT,
    short* __restrict__ WvT, short* __restrict__ WoT,
    short* __restrict__ W1T, short* __restrict__ W2T){
  __shared__ float tile[32][33];
  int bid = blockIdx.x;
  const float* W; short* WT; int K, N, t0;
  if      (bid <  256){ W=Wq; WT=WqT; K=512;  N=512;  t0=0;    }
  else if (bid <  512){ W=Wk; WT=WkT; K=512;  N=512;  t0=256;  }
  else if (bid <  768){ W=Wv; WT=WvT; K=512;  N=512;  t0=512;  }
  else if (bid < 1024){ W=Wo; WT=WoT; K=512;  N=512;  t0=768;  }
  else if (bid < 2048){ W=W1; WT=W1T; K=512;  N=2048; t0=1024; }
  else                { W=W2; WT=W2T; K=2048; N=512;  t0=2048; }
  int lt = bid - t0;
  int ntn = N / 32;
  int tk = lt / ntn, tn = lt % ntn;
  int r0 = threadIdx.x >> 5, c = threadIdx.x & 31;
  #pragma unroll
  for (int i = 0; i < 4; ++i){
    int r = r0 + i*8;
    tile[r][c] = W[(long)(tk*32 + r)*N + tn*32 + c];
  }
  __syncthreads();
  #pragma unroll
  for (int i = 0; i < 4; ++i){
    int r = r0 + i*8;
    WT[(long)(tn*32 + r)*K + tk*32 + c] = f2bf(tile[c][r]);
  }
}

// ---------------- generic bf16 MFMA GEMM: C[M,N] = A[M,K] @ Bt[N,K]^T --------
// 128x128 tile, BK=32, 4 waves (each 64x64), global_load_lds staging with
// pre-swizzled source (XOR 16B-slot by (row>>1)&3) to kill ds_read conflicts.
__global__ __launch_bounds__(256) void gemm_bt(
    const short* __restrict__ A, const short* __restrict__ Bt,
    short* __restrict__ C, const float* __restrict__ bias,
    int M, int N, int K, float scale, int relu, int colmajor){
  __shared__ __align__(16) short Als[128*32];
  __shared__ __align__(16) short Bls[128*32];
  int tid = threadIdx.x;
  int lane = tid & 63, w = tid >> 6;
  int wm = w >> 1, wn = w & 1;
  int l15 = lane & 15, l4 = lane >> 4;
  long brow = (long)blockIdx.y * 128;
  long bcol = (long)blockIdx.x * 128;

  f4v acc[4][4];
  #pragma unroll
  for (int m = 0; m < 4; ++m)
    #pragma unroll
    for (int n = 0; n < 4; ++n) acc[m][n] = (f4v){0.f,0.f,0.f,0.f};

  for (int t = 0; t < K; t += 32){
    #pragma unroll
    for (int i = 0; i < 2; ++i){
      int c = i*256 + tid;
      int row = c >> 2, slot = c & 3;
      int cg = slot ^ ((row >> 1) & 3);   // inverse-swizzled global source
      long ar = brow + row; if (ar >= M) ar = M - 1;
      gload16(A + ar*(long)K + t + cg*8, &Als[c*8]);
      long br = bcol + row; if (br >= N) br = N - 1;
      gload16(Bt + br*(long)K + t + cg*8, &Bls[c*8]);
    }
    __syncthreads();
    bf8v a[4], b[4];
    #pragma unroll
    for (int m = 0; m < 4; ++m){
      int row = wm*64 + m*16 + l15;
      int slot = l4 ^ ((row >> 1) & 3);
      a[m] = *(const bf8v*)&Als[row*32 + slot*8];
    }
    #pragma unroll
    for (int n = 0; n < 4; ++n){
      int row = wn*64 + n*16 + l15;
      int slot = l4 ^ ((row >> 1) & 3);
      b[n] = *(const bf8v*)&Bls[row*32 + slot*8];
    }
    #pragma unroll
    for (int m = 0; m < 4; ++m)
      #pragma unroll
      for (int n = 0; n < 4; ++n)
        acc[m][n] = __builtin_amdgcn_mfma_f32_16x16x32_bf16(a[m], b[n], acc[m][n], 0, 0, 0);
    __syncthreads();
  }

  #pragma unroll
  for (int m = 0; m < 4; ++m){
    #pragma unroll
    for (int n = 0; n < 4; ++n){
      long col = bcol + wn*64 + n*16 + l15;
      float bi = (bias != nullptr && col < N) ? bias[col] : 0.f;
      #pragma unroll
      for (int j = 0; j < 4; ++j){
        long row = brow + wm*64 + m*16 + 4*l4 + j;
        if (row < M && col < N){
          float v = acc[m][n][j] * scale + bi;
          if (relu) v = fmaxf(v, 0.f);
          C[colmajor ? (col*(long)M + row) : (row*(long)N + col)] = f2bf(v);
        }
      }
    }
  }
}

// ---------------- flash attention over packed batches ------------------------
// block = (qtile of 64, head, batch); 4 waves x 16 q-rows; kv tiles of 64.
__global__ __launch_bounds__(256) void attn_kernel(
    const short* __restrict__ Q, const short* __restrict__ Kb,
    const short* __restrict__ Vt, short* __restrict__ Ob,
    const int* __restrict__ meta, int total){
  int qt = blockIdx.x, h = blockIdx.y, b = blockIdx.z;
  int Lx = meta[b], Lm = meta[8+b];
  int ox = meta[16+b], om = meta[25+b];
  if (qt*64 >= Lx) return;

  __shared__ __align__(16) short Kls[64*64];
  __shared__ __align__(16) short Vls[64*64];
  __shared__ __align__(16) short Pls[4*16*64];

  int tid = threadIdx.x;
  int lane = tid & 63, w = tid >> 6;
  int l15 = lane & 15, l4 = lane >> 4;

  // Q fragments (held in regs for all kv tiles); 1/sqrt(dh) pre-folded into Q.
  bf8v aq0, aq1;
  {
    int qrow = qt*64 + w*16 + l15;
    int grow = ox + (qrow < Lx ? qrow : Lx - 1);
    const short* qp = Q + (long)grow*512 + h*64 + l4*8;
    aq0 = *(const bf8v*)qp;
    aq1 = *(const bf8v*)(qp + 32);
  }
  float mrun[4] = {-1e30f,-1e30f,-1e30f,-1e30f};
  float lrun[4] = {0.f,0.f,0.f,0.f};
  f4v o[4];
  #pragma unroll
  for (int n = 0; n < 4; ++n) o[n] = (f4v){0.f,0.f,0.f,0.f};

  for (int kv0 = 0; kv0 < Lm; kv0 += 64){
    // stage K (rows=kv, 128B each) and Vt (rows=dh col, 128B each), swizzled
    #pragma unroll
    for (int i = 0; i < 2; ++i){
      int c = i*256 + tid;
      int rr = c >> 3, slot = c & 7;
      int ch = slot ^ (rr & 7);
      int tok = kv0 + rr; if (tok >= Lm) tok = Lm - 1;
      gload16(Kb + (long)(om + tok)*512 + h*64 + ch*8, &Kls[c*8]);
      int kvs = kv0 + ch*8; if (kvs + 8 > Lm) kvs = Lm - 8;
      gload16(Vt + (long)(h*64 + rr)*total + om + kvs, &Vls[c*8]);
    }
    __syncthreads();

    // S = Q K^T  (per wave: 16q x 64kv)
    f4v s[4];
    #pragma unroll
    for (int n = 0; n < 4; ++n){
      int kvrow = n*16 + l15;
      int sl0 = l4 ^ (kvrow & 7);
      int sl1 = (4 + l4) ^ (kvrow & 7);
      bf8v b0 = *(const bf8v*)&Kls[kvrow*64 + sl0*8];
      bf8v b1 = *(const bf8v*)&Kls[kvrow*64 + sl1*8];
      f4v z = (f4v){0.f,0.f,0.f,0.f};
      z = __builtin_amdgcn_mfma_f32_16x16x32_bf16(aq0, b0, z, 0, 0, 0);
      z = __builtin_amdgcn_mfma_f32_16x16x32_bf16(aq1, b1, z, 0, 0, 0);
      s[n] = z;
    }
    // mask invalid kv columns
    #pragma unroll
    for (int n = 0; n < 4; ++n){
      if (kv0 + n*16 + l15 >= Lm){
        s[n][0] = -1e30f; s[n][1] = -1e30f; s[n][2] = -1e30f; s[n][3] = -1e30f;
      }
    }
    // online softmax (row = 4*l4 + j, 16 lanes per row share via shfl_xor)
    #pragma unroll
    for (int j = 0; j < 4; ++j){
      float m1 = fmaxf(fmaxf(s[0][j], s[1][j]), fmaxf(s[2][j], s[3][j]));
      m1 = fmaxf(m1, __shfl_xor(m1, 1, 64));
      m1 = fmaxf(m1, __shfl_xor(m1, 2, 64));
      m1 = fmaxf(m1, __shfl_xor(m1, 4, 64));
      m1 = fmaxf(m1, __shfl_xor(m1, 8, 64));
      float mnew = fmaxf(mrun[j], m1);
      float sc = __expf(mrun[j] - mnew);
      float rs = 0.f;
      #pragma unroll
      for (int n = 0; n < 4; ++n){
        float p = __expf(s[n][j] - mnew);
        s[n][j] = p; rs += p;
      }
      rs += __shfl_xor(rs, 1, 64); rs += __shfl_xor(rs, 2, 64);
      rs += __shfl_xor(rs, 4, 64); rs += __shfl_xor(rs, 8, 64);
      lrun[j] = lrun[j] * sc + rs;
      mrun[j] = mnew;
      o[0][j] *= sc; o[1][j] *= sc; o[2][j] *= sc; o[3][j] *= sc;
    }
    // P -> wave-private LDS (bf16, swizzled) to re-fragment for PV
    #pragma unroll
    for (int n = 0; n < 4; ++n){
      int pcol = n*16 + l15;
      #pragma unroll
      for (int j = 0; j < 4; ++j){
        int prow = 4*l4 + j;
        Pls[w*1024 + prow*64 + (((pcol >> 3) ^ (prow & 7)) << 3) + (pcol & 7)] = f2bf(s[n][j]);
      }
    }
    // O += P @ V
    #pragma unroll
    for (int ks = 0; ks < 2; ++ks){
      int ch = ks*4 + l4;
      bf8v ap = *(const bf8v*)&Pls[w*1024 + l15*64 + ((ch ^ (l15 & 7)) << 3)];
      #pragma unroll
      for (int n = 0; n < 4; ++n){
        int d = n*16 + l15;
        bf8v bv = *(const bf8v*)&Vls[d*64 + ((ch ^ (d & 7)) << 3)];
        o[n] = __builtin_amdgcn_mfma_f32_16x16x32_bf16(ap, bv, o[n], 0, 0, 0);
      }
    }
    __syncthreads();
  }

  #pragma unroll
  for (int n = 0; n < 4; ++n){
    #pragma unroll
    for (int j = 0; j < 4; ++j){
      int qrow = qt*64 + w*16 + 4*l4 + j;
      if (qrow < Lx){
        float val = o[n][j] / lrun[j];
        Ob[(long)(ox + qrow)*512 + h*64 + n*16 + l15] = f2bf(val);
      }
    }
  }
}

// ---------------- fused residual + LayerNorm (wave per 512-col row) ----------
__global__ __launch_bounds__(256) void ln_fuse(
    const float* __restrict__ Af, const short* __restrict__ Ab,
    const short* __restrict__ Bb,
    const float* __restrict__ gamma, const float* __restrict__ beta,
    short* __restrict__ outb, float* __restrict__ outf, int rows){
  int w = threadIdx.x >> 6, lane = threadIdx.x & 63;
  long row = (long)blockIdx.x * 4 + w;
  if (row >= rows) return;
  int c0 = lane * 8;
  long base = row * 512 + c0;
  float v[8];
  if (Af){
    float4 f0 = *(const float4*)(Af + base);
    float4 f1 = *(const float4*)(Af + base + 4);
    v[0]=f0.x; v[1]=f0.y; v[2]=f0.z; v[3]=f0.w;
    v[4]=f1.x; v[5]=f1.y; v[6]=f1.z; v[7]=f1.w;
  } else {
    s8v a = *(const s8v*)(Ab + base);
    #pragma unroll
    for (int j = 0; j < 8; ++j) v[j] = bf2f(a[j]);
  }
  s8v bb = *(const s8v*)(Bb + base);
  #pragma unroll
  for (int j = 0; j < 8; ++j) v[j] += bf2f(bb[j]);
  float sum = 0.f;
  #pragma unroll
  for (int j = 0; j < 8; ++j) sum += v[j];
  #pragma unroll
  for (int m = 1; m < 64; m <<= 1) sum += __shfl_xor(sum, m, 64);
  float mu = sum * (1.f/512.f);
  float q = 0.f;
  #pragma unroll
  for (int j = 0; j < 8; ++j){ float d = v[j] - mu; q += d*d; }
  #pragma unroll
  for (int m = 1; m < 64; m <<= 1) q += __shfl_xor(q, m, 64);
  float rs = rsqrtf(q * (1.f/512.f) + 1e-6f);
  float ov[8];
  #pragma unroll
  for (int j = 0; j < 8; ++j)
    ov[j] = (v[j] - mu) * rs * gamma[c0 + j] + beta[c0 + j];
  if (outb){
    s8v os;
    #pragma unroll
    for (int j = 0; j < 8; ++j) os[j] = f2bf(ov[j]);
    *(s8v*)(outb + base) = os;
  } else {
    float4 f0 = {ov[0], ov[1], ov[2], ov[3]};
    float4 f1 = {ov[4], ov[5], ov[6], ov[7]};
    *(float4*)(outf + base) = f0;
    *(float4*)(outf + base + 4) = f1;
  }
}

// ---------------- host ------------------------------------------------------
extern "C" void kernel_launch(void* const* d_in, const int* in_sizes, int n_in,
                              void* d_out, int out_size, void* d_ws, size_t ws_size,
                              hipStream_t stream){
  (void)n_in; (void)out_size; (void)ws_size;
  const float* x   = (const float*)d_in[0];
  const float* mem = (const float*)d_in[1];
  const int*   lxr = (const int*)d_in[2];
  const int*   lmr = (const int*)d_in[3];
  const float* Wq  = (const float*)d_in[4];
  const float* Wk  = (const float*)d_in[5];
  const float* Wv  = (const float*)d_in[6];
  const float* Wo  = (const float*)d_in[7];
  const float* g1  = (const float*)d_in[8];
  const float* be1 = (const float*)d_in[9];
  const float* W1  = (const float*)d_in[10];
  const float* b1  = (const float*)d_in[11];
  const float* W2  = (const float*)d_in[12];
  const float* b2  = (const float*)d_in[13];
  const float* g2  = (const float*)d_in[14];
  const float* be2 = (const float*)d_in[15];
  float* out = (float*)d_out;

  int total = in_sizes[0] / 512;
  if (total <= 0) return;
  long long n = (long long)total * 512;

  char* p = (char*)d_ws;
  int*   meta = (int*)p;    p += 256;
  short* xb   = (short*)p;  p += n*2;
  short* mb   = (short*)p;  p += n*2;
  short* Qb   = (short*)p;  p += n*2;
  short* Kbf  = (short*)p;  p += n*2;
  short* Vtb  = (short*)p;  p += n*2;
  short* attnb= (short*)p;  p += n*2;
  short* woout= (short*)p;  p += n*2;
  short* hb   = (short*)p;  p += n*2;
  short* ffn1 = (short*)p;  p += (long long)total*2048*2;
  short* ffn2 = (short*)p;  p += n*2;
  short* WqT  = (short*)p;  p += 512*512*2;
  short* WkT  = (short*)p;  p += 512*512*2;
  short* WvT  = (short*)p;  p += 512*512*2;
  short* WoT  = (short*)p;  p += 512*512*2;
  short* W1T  = (short*)p;  p += 2048*512*2;
  short* W2T  = (short*)p;  p += 512*2048*2;

  prep_kernel<<<1, 64, 0, stream>>>(lxr, lmr, meta);

  long long th = (2*n)/8;
  cvt2bf<<<dim3((unsigned)((th + 255)/256)), dim3(256), 0, stream>>>(x, mem, xb, mb, n);
  cvt_w_t<<<dim3(3072), dim3(256), 0, stream>>>(Wq,Wk,Wv,Wo,W1,W2, WqT,WkT,WvT,WoT,W1T,W2T);

  int mt = (total + 127)/128;
  // Q (scale 1/8 folded), K, V (column-major out)
  gemm_bt<<<dim3(4, mt), 256, 0, stream>>>(xb, WqT, Qb,  nullptr, total, 512, 512, 0.125f, 0, 0);
  gemm_bt<<<dim3(4, mt), 256, 0, stream>>>(mb, WkT, Kbf, nullptr, total, 512, 512, 1.f,    0, 0);
  gemm_bt<<<dim3(4, mt), 256, 0, stream>>>(mb, WvT, Vtb, nullptr, total, 512, 512, 1.f,    0, 1);

  attn_kernel<<<dim3((unsigned)((total + 63)/64), 8, 8), 256, 0, stream>>>(Qb, Kbf, Vtb, attnb, meta, total);

  gemm_bt<<<dim3(4, mt), 256, 0, stream>>>(attnb, WoT, woout, nullptr, total, 512, 512, 1.f, 0, 0);
  ln_fuse<<<dim3((unsigned)((total + 3)/4)), 256, 0, stream>>>(x, nullptr, woout, g1, be1, hb, nullptr, total);

  gemm_bt<<<dim3(16, mt), 256, 0, stream>>>(hb,   W1T, ffn1, b1, total, 2048, 512,  1.f, 1, 0);
  gemm_bt<<<dim3(4,  mt), 256, 0, stream>>>(ffn1, W2T, ffn2, b2, total, 512,  2048, 1.f, 0, 0);
  ln_fuse<<<dim3((unsigned)((total + 3)/4)), 256, 0, stream>>>(nullptr, hb, ffn2, g2, be2, nullptr, out, total);
}

// Round 2
// 204.535 us; speedup vs baseline: 1.1765x; 1.1765x over previous
//
#include <hip/hip_runtime.h>
#include <stdint.h>

typedef short bf8v __attribute__((ext_vector_type(8)));
typedef float f4v  __attribute__((ext_vector_type(4)));
typedef short s8v  __attribute__((ext_vector_type(8)));

__device__ __forceinline__ float bf2f(short b){
  unsigned u = ((unsigned)(unsigned short)b) << 16;
  union { unsigned u; float f; } c; c.u = u; return c.f;
}
__device__ __forceinline__ short f2bf(float f){
  union { float f; unsigned u; } c; c.f = f;
  unsigned r = (c.u + 0x7FFFu + ((c.u >> 16) & 1u)) >> 16;
  return (short)r;
}
__device__ __forceinline__ void gload16(const short* g, short* l){
  __builtin_amdgcn_global_load_lds(
      (const __attribute__((address_space(1))) void*)g,
      (__attribute__((address_space(3))) void*)l, 16, 0, 0);
}

// ---------------- prep: lengths -> offsets (int32/int64 autodetect) ----------
__global__ void prep_kernel(const int* lx, const int* lm, int* meta){
  if (threadIdx.x != 0) return;
  int is64 = ((lx[1] | lx[3] | lx[5] | lx[7]) == 0) ? 1 : 0;
  int ox = 0, om = 0;
  for (int b = 0; b < 8; ++b){
    int a = is64 ? lx[2*b] : lx[b];
    int c = is64 ? lm[2*b] : lm[b];
    meta[b] = a; meta[8+b] = c;
    meta[16+b] = ox; meta[25+b] = om;
    ox += a; om += c;
  }
  meta[24] = ox; meta[33] = om;
}

// ---------------- f32 -> bf16 conversion for x and mem -----------------------
__global__ __launch_bounds__(256) void cvt2bf(const float* __restrict__ x,
                                              const float* __restrict__ mem,
                                              short* __restrict__ xb,
                                              short* __restrict__ mb,
                                              long long n){
  long long t = (long long)blockIdx.x * 256 + threadIdx.x;
  long long i = t * 8;
  const float* s; short* d;
  if (i < n){ s = x + i; d = xb + i; }
  else {
    i -= n; if (i >= n) return;
    s = mem + i; d = mb + i;
  }
  float4 f0 = *(const float4*)s;
  float4 f1 = *(const float4*)(s + 4);
  s8v o;
  o[0]=f2bf(f0.x); o[1]=f2bf(f0.y); o[2]=f2bf(f0.z); o[3]=f2bf(f0.w);
  o[4]=f2bf(f1.x); o[5]=f2bf(f1.y); o[6]=f2bf(f1.z); o[7]=f2bf(f1.w);
  *(s8v*)d = o;
}

// ---------------- weight transpose + convert: W[K][N] -> WT[N][K] bf16 -------
__global__ __launch_bounds__(256) void cvt_w_t(
    const float* __restrict__ Wq, const float* __restrict__ Wk,
    const float* __restrict__ Wv, const float* __restrict__ Wo,
    const float* __restrict__ W1, const float* __restrict__ W2,
    short* __restrict__ WqT, short* __restrict__ WkT,
    short* __restrict__ WvT, short* __restrict__ WoT,
    short* __restrict__ W1T, short* __restrict__ W2T){
  __shared__ float tile[32][33];
  int bid = blockIdx.x;
  const float* W; short* WT; int K, N, t0;
  if      (bid <  256){ W=Wq; WT=WqT; K=512;  N=512;  t0=0;    }
  else if (bid <  512){ W=Wk; WT=WkT; K=512;  N=512;  t0=256;  }
  else if (bid <  768){ W=Wv; WT=WvT; K=512;  N=512;  t0=512;  }
  else if (bid < 1024){ W=Wo; WT=WoT; K=512;  N=512;  t0=768;  }
  else if (bid < 2048){ W=W1; WT=W1T; K=512;  N=2048; t0=1024; }
  else                { W=W2; WT=W2T; K=2048; N=512;  t0=2048; }
  int lt = bid - t0;
  int ntn = N / 32;
  int tk = lt / ntn, tn = lt % ntn;
  int r0 = threadIdx.x >> 5, c = threadIdx.x & 31;
  #pragma unroll
  for (int i = 0; i < 4; ++i){
    int r = r0 + i*8;
    tile[r][c] = W[(long)(tk*32 + r)*N + tn*32 + c];
  }
  __syncthreads();
  #pragma unroll
  for (int i = 0; i < 4; ++i){
    int r = r0 + i*8;
    WT[(long)(tn*32 + r)*K + tk*32 + c] = f2bf(tile[c][r]);
  }
}

// ---------------- generic bf16 MFMA GEMM core: C[M,N] = A[M,K] @ Bt[N,K]^T ---
// 128x128 tile, BK=32, 4 waves, double-buffered global_load_lds staging with
// early issue (2-phase pipeline), pre-swizzled source to kill ds conflicts.
__device__ __forceinline__ void stage_gemm(const short* A, const short* Bt,
    long brow, long bcol, int M, int N, int K, int t,
    short* Als, short* Bls){
  int tid = threadIdx.x;
  #pragma unroll
  for (int i = 0; i < 2; ++i){
    int c = i*256 + tid;
    int row = c >> 2, slot = c & 3;
    int cg = slot ^ ((row >> 1) & 3);
    long ar = brow + row; if (ar >= M) ar = M - 1;
    gload16(A + ar*(long)K + t + cg*8, &Als[c*8]);
    long br = bcol + row; if (br >= N) br = N - 1;
    gload16(Bt + br*(long)K + t + cg*8, &Bls[c*8]);
  }
}

__device__ __forceinline__ void gemm_core(const short* A, const short* Bt,
    short* __restrict__ C, const float* __restrict__ bias,
    int M, int N, int K, float scale, int relu, int colmajor,
    long brow, long bcol, short* Als, short* Bls){
  int tid = threadIdx.x;
  int lane = tid & 63, w = tid >> 6;
  int wm = w >> 1, wn = w & 1;
  int l15 = lane & 15, l4 = lane >> 4;

  f4v acc[4][4];
  #pragma unroll
  for (int m = 0; m < 4; ++m)
    #pragma unroll
    for (int n = 0; n < 4; ++n) acc[m][n] = (f4v){0.f,0.f,0.f,0.f};

  int nt = K / 32;
  stage_gemm(A, Bt, brow, bcol, M, N, K, 0, Als, Bls);
  for (int t = 0; t < nt; ++t){
    __syncthreads();             // drains vmcnt: buf[t&1] ready, buf[nxt] free
    if (t + 1 < nt)
      stage_gemm(A, Bt, brow, bcol, M, N, K, (t+1)*32,
                 Als + ((t+1)&1)*4096, Bls + ((t+1)&1)*4096);
    const short* Ab = Als + (t&1)*4096;
    const short* Bb = Bls + (t&1)*4096;
    bf8v a[4], b[4];
    #pragma unroll
    for (int m = 0; m < 4; ++m){
      int row = wm*64 + m*16 + l15;
      int slot = l4 ^ ((row >> 1) & 3);
      a[m] = *(const bf8v*)&Ab[row*32 + slot*8];
    }
    #pragma unroll
    for (int n = 0; n < 4; ++n){
      int row = wn*64 + n*16 + l15;
      int slot = l4 ^ ((row >> 1) & 3);
      b[n] = *(const bf8v*)&Bb[row*32 + slot*8];
    }
    #pragma unroll
    for (int m = 0; m < 4; ++m)
      #pragma unroll
      for (int n = 0; n < 4; ++n)
        acc[m][n] = __builtin_amdgcn_mfma_f32_16x16x32_bf16(a[m], b[n], acc[m][n], 0, 0, 0);
  }

  #pragma unroll
  for (int m = 0; m < 4; ++m){
    #pragma unroll
    for (int n = 0; n < 4; ++n){
      long col = bcol + wn*64 + n*16 + l15;
      float bi = (bias != nullptr && col < N) ? bias[col] : 0.f;
      #pragma unroll
      for (int j = 0; j < 4; ++j){
        long row = brow + wm*64 + m*16 + 4*l4 + j;
        if (row < M && col < N){
          float v = acc[m][n][j] * scale + bi;
          if (relu) v = fmaxf(v, 0.f);
          C[colmajor ? (col*(long)M + row) : (row*(long)N + col)] = f2bf(v);
        }
      }
    }
  }
}

__global__ __launch_bounds__(256) void gemm_bt(
    const short* __restrict__ A, const short* __restrict__ Bt,
    short* __restrict__ C, const float* __restrict__ bias,
    int M, int N, int K, float scale, int relu, int colmajor){
  __shared__ __align__(16) short Als[2*128*32];
  __shared__ __align__(16) short Bls[2*128*32];
  gemm_core(A, Bt, C, bias, M, N, K, scale, relu, colmajor,
            (long)blockIdx.y * 128, (long)blockIdx.x * 128, Als, Bls);
}

// fused QKV: grid.x = 12 (4 col-tiles x {Q,K,V}); Q from xb, K/V from mb.
__global__ __launch_bounds__(256) void gemm_qkv(
    const short* __restrict__ xb, const short* __restrict__ mb,
    const short* __restrict__ WqT, const short* __restrict__ WkT,
    const short* __restrict__ WvT,
    short* __restrict__ Qb, short* __restrict__ Kbf, short* __restrict__ Vtb,
    int total){
  __shared__ __align__(16) short Als[2*128*32];
  __shared__ __align__(16) short Bls[2*128*32];
  int seg = blockIdx.x >> 2;
  const short* A  = (seg == 0) ? xb : mb;
  const short* Bt = (seg == 0) ? WqT : ((seg == 1) ? WkT : WvT);
  short* C        = (seg == 0) ? Qb  : ((seg == 1) ? Kbf : Vtb);
  float scale     = (seg == 0) ? 0.125f : 1.f;
  int colmajor    = (seg == 2);
  gemm_core(A, Bt, C, nullptr, total, 512, 512, scale, 0, colmajor,
            (long)blockIdx.y * 128, (long)(blockIdx.x & 3) * 128, Als, Bls);
}

// ---------------- flash attention over packed batches ------------------------
// block = (qtile of 128, head, batch); 8 waves x 16 q-rows; kv tiles of 64,
// double-buffered K/V staging with early issue.
__global__ __launch_bounds__(512) void attn_kernel(
    const short* __restrict__ Q, const short* __restrict__ Kb,
    const short* __restrict__ Vt, short* __restrict__ Ob,
    const int* __restrict__ meta, int total){
  int qt = blockIdx.x, h = blockIdx.y, b = blockIdx.z;
  int Lx = meta[b], Lm = meta[8+b];
  int ox = meta[16+b], om = meta[25+b];
  if (qt*128 >= Lx) return;

  __shared__ __align__(16) short Kls[2][64*64];
  __shared__ __align__(16) short Vls[2][64*64];
  __shared__ __align__(16) short Pls[8][16*64];

  int tid = threadIdx.x;
  int lane = tid & 63, w = tid >> 6;
  int l15 = lane & 15, l4 = lane >> 4;

  // Q fragments (1/sqrt(dh) pre-folded into Q by the QKV GEMM).
  bf8v aq0, aq1;
  {
    int qrow = qt*128 + w*16 + l15;
    int grow = ox + (qrow < Lx ? qrow : Lx - 1);
    const short* qp = Q + (long)grow*512 + h*64 + l4*8;
    aq0 = *(const bf8v*)qp;
    aq1 = *(const bf8v*)(qp + 32);
  }
  float mrun[4] = {-1e30f,-1e30f,-1e30f,-1e30f};
  float lrun[4] = {0.f,0.f,0.f,0.f};
  f4v o[4];
  #pragma unroll
  for (int n = 0; n < 4; ++n) o[n] = (f4v){0.f,0.f,0.f,0.f};

  int nt = (Lm + 63) / 64;

  // staging helper: each of 512 threads loads one 16B K chunk + one 16B V chunk
  #define ATTN_STAGE(T, BUF)                                                   \
    {                                                                          \
      int c = tid;                                                             \
      int rr = c >> 3, slot = c & 7;                                           \
      int ch = slot ^ (rr & 7);                                                \
      int kv0_ = (T) * 64;                                                     \
      int tok = kv0_ + rr; if (tok >= Lm) tok = Lm - 1;                        \
      gload16(Kb + (long)(om + tok)*512 + h*64 + ch*8, &Kls[BUF][c*8]);        \
      int kvs = kv0_ + ch*8; if (kvs + 8 > Lm) kvs = Lm - 8;                   \
      gload16(Vt + (long)(h*64 + rr)*total + om + kvs, &Vls[BUF][c*8]);        \
    }

  ATTN_STAGE(0, 0)
  for (int t = 0; t < nt; ++t){
    __syncthreads();                       // buf[t&1] ready; buf[nxt] free
    if (t + 1 < nt) ATTN_STAGE(t+1, (t+1)&1)
    int buf = t & 1;
    int kv0 = t * 64;

    // S = Q K^T  (per wave: 16q x 64kv)
    f4v s[4];
    #pragma unroll
    for (int n = 0; n < 4; ++n){
      int kvrow = n*16 + l15;
      int sl0 = l4 ^ (kvrow & 7);
      int sl1 = (4 + l4) ^ (kvrow & 7);
      bf8v b0 = *(const bf8v*)&Kls[buf][kvrow*64 + sl0*8];
      bf8v b1 = *(const bf8v*)&Kls[buf][kvrow*64 + sl1*8];
      f4v z = (f4v){0.f,0.f,0.f,0.f};
      z = __builtin_amdgcn_mfma_f32_16x16x32_bf16(aq0, b0, z, 0, 0, 0);
      z = __builtin_amdgcn_mfma_f32_16x16x32_bf16(aq1, b1, z, 0, 0, 0);
      s[n] = z;
    }
    // mask invalid kv columns
    #pragma unroll
    for (int n = 0; n < 4; ++n){
      if (kv0 + n*16 + l15 >= Lm){
        s[n][0] = -1e30f; s[n][1] = -1e30f; s[n][2] = -1e30f; s[n][3] = -1e30f;
      }
    }
    // online softmax (row = 4*l4 + j, 16 lanes per row share via shfl_xor)
    #pragma unroll
    for (int j = 0; j < 4; ++j){
      float m1 = fmaxf(fmaxf(s[0][j], s[1][j]), fmaxf(s[2][j], s[3][j]));
      m1 = fmaxf(m1, __shfl_xor(m1, 1, 64));
      m1 = fmaxf(m1, __shfl_xor(m1, 2, 64));
      m1 = fmaxf(m1, __shfl_xor(m1, 4, 64));
      m1 = fmaxf(m1, __shfl_xor(m1, 8, 64));
      float mnew = fmaxf(mrun[j], m1);
      float sc = __expf(mrun[j] - mnew);
      float rs = 0.f;
      #pragma unroll
      for (int n = 0; n < 4; ++n){
        float p = __expf(s[n][j] - mnew);
        s[n][j] = p; rs += p;
      }
      rs += __shfl_xor(rs, 1, 64); rs += __shfl_xor(rs, 2, 64);
      rs += __shfl_xor(rs, 4, 64); rs += __shfl_xor(rs, 8, 64);
      lrun[j] = lrun[j] * sc + rs;
      mrun[j] = mnew;
      o[0][j] *= sc; o[1][j] *= sc; o[2][j] *= sc; o[3][j] *= sc;
    }
    // P -> wave-private LDS (bf16, swizzled) to re-fragment for PV
    #pragma unroll
    for (int n = 0; n < 4; ++n){
      int pcol = n*16 + l15;
      #pragma unroll
      for (int j = 0; j < 4; ++j){
        int prow = 4*l4 + j;
        Pls[w][prow*64 + (((pcol >> 3) ^ (prow & 7)) << 3) + (pcol & 7)] = f2bf(s[n][j]);
      }
    }
    // O += P @ V
    #pragma unroll
    for (int ks = 0; ks < 2; ++ks){
      int ch = ks*4 + l4;
      bf8v ap = *(const bf8v*)&Pls[w][l15*64 + ((ch ^ (l15 & 7)) << 3)];
      #pragma unroll
      for (int n = 0; n < 4; ++n){
        int d = n*16 + l15;
        bf8v bv = *(const bf8v*)&Vls[buf][d*64 + ((ch ^ (d & 7)) << 3)];
        o[n] = __builtin_amdgcn_mfma_f32_16x16x32_bf16(ap, bv, o[n], 0, 0, 0);
      }
    }
  }
  #undef ATTN_STAGE

  #pragma unroll
  for (int n = 0; n < 4; ++n){
    #pragma unroll
    for (int j = 0; j < 4; ++j){
      int qrow = qt*128 + w*16 + 4*l4 + j;
      if (qrow < Lx){
        float val = o[n][j] / lrun[j];
        Ob[(long)(ox + qrow)*512 + h*64 + n*16 + l15] = f2bf(val);
      }
    }
  }
}

// ---------------- fused residual + LayerNorm (wave per 512-col row) ----------
__global__ __launch_bounds__(256) void ln_fuse(
    const float* __restrict__ Af, const short* __restrict__ Ab,
    const short* __restrict__ Bb,
    const float* __restrict__ gamma, const float* __restrict__ beta,
    short* __restrict__ outb, float* __restrict__ outf, int rows){
  int w = threadIdx.x >> 6, lane = threadIdx.x & 63;
  long row = (long)blockIdx.x * 4 + w;
  if (row >= rows) return;
  int c0 = lane * 8;
  long base = row * 512 + c0;
  float v[8];
  if (Af){
    float4 f0 = *(const float4*)(Af + base);
    float4 f1 = *(const float4*)(Af + base + 4);
    v[0]=f0.x; v[1]=f0.y; v[2]=f0.z; v[3]=f0.w;
    v[4]=f1.x; v[5]=f1.y; v[6]=f1.z; v[7]=f1.w;
  } else {
    s8v a = *(const s8v*)(Ab + base);
    #pragma unroll
    for (int j = 0; j < 8; ++j) v[j] = bf2f(a[j]);
  }
  s8v bb = *(const s8v*)(Bb + base);
  #pragma unroll
  for (int j = 0; j < 8; ++j) v[j] += bf2f(bb[j]);
  float sum = 0.f;
  #pragma unroll
  for (int j = 0; j < 8; ++j) sum += v[j];
  #pragma unroll
  for (int m = 1; m < 64; m <<= 1) sum += __shfl_xor(sum, m, 64);
  float mu = sum * (1.f/512.f);
  float q = 0.f;
  #pragma unroll
  for (int j = 0; j < 8; ++j){ float d = v[j] - mu; q += d*d; }
  #pragma unroll
  for (int m = 1; m < 64; m <<= 1) q += __shfl_xor(q, m, 64);
  float rs = rsqrtf(q * (1.f/512.f) + 1e-6f);
  float ov[8];
  #pragma unroll
  for (int j = 0; j < 8; ++j)
    ov[j] = (v[j] - mu) * rs * gamma[c0 + j] + beta[c0 + j];
  if (outb){
    s8v os;
    #pragma unroll
    for (int j = 0; j < 8; ++j) os[j] = f2bf(ov[j]);
    *(s8v*)(outb + base) = os;
  } else {
    float4 f0 = {ov[0], ov[1], ov[2], ov[3]};
    float4 f1 = {ov[4], ov[5], ov[6], ov[7]};
    *(float4*)(outf + base) = f0;
    *(float4*)(outf + base + 4) = f1;
  }
}

// ---------------- host ------------------------------------------------------
extern "C" void kernel_launch(void* const* d_in, const int* in_sizes, int n_in,
                              void* d_out, int out_size, void* d_ws, size_t ws_size,
                              hipStream_t stream){
  (void)n_in; (void)out_size; (void)ws_size;
  const float* x   = (const float*)d_in[0];
  const float* mem = (const float*)d_in[1];
  const int*   lxr = (const int*)d_in[2];
  const int*   lmr = (const int*)d_in[3];
  const float* Wq  = (const float*)d_in[4];
  const float* Wk  = (const float*)d_in[5];
  const float* Wv  = (const float*)d_in[6];
  const float* Wo  = (const float*)d_in[7];
  const float* g1  = (const float*)d_in[8];
  const float* be1 = (const float*)d_in[9];
  const float* W1  = (const float*)d_in[10];
  const float* b1  = (const float*)d_in[11];
  const float* W2  = (const float*)d_in[12];
  const float* b2  = (const float*)d_in[13];
  const float* g2  = (const float*)d_in[14];
  const float* be2 = (const float*)d_in[15];
  float* out = (float*)d_out;

  int total = in_sizes[0] / 512;
  if (total <= 0) return;
  long long n = (long long)total * 512;

  char* p = (char*)d_ws;
  int*   meta = (int*)p;    p += 256;
  short* xb   = (short*)p;  p += n*2;
  short* mb   = (short*)p;  p += n*2;
  short* Qb   = (short*)p;  p += n*2;
  short* Kbf  = (short*)p;  p += n*2;
  short* Vtb  = (short*)p;  p += n*2;
  short* attnb= (short*)p;  p += n*2;
  short* woout= (short*)p;  p += n*2;
  short* hb   = (short*)p;  p += n*2;
  short* ffn1 = (short*)p;  p += (long long)total*2048*2;
  short* ffn2 = (short*)p;  p += n*2;
  short* WqT  = (short*)p;  p += 512*512*2;
  short* WkT  = (short*)p;  p += 512*512*2;
  short* WvT  = (short*)p;  p += 512*512*2;
  short* WoT  = (short*)p;  p += 512*512*2;
  short* W1T  = (short*)p;  p += 2048*512*2;
  short* W2T  = (short*)p;  p += 512*2048*2;

  prep_kernel<<<1, 64, 0, stream>>>(lxr, lmr, meta);

  long long th = (2*n)/8;
  cvt2bf<<<dim3((unsigned)((th + 255)/256)), dim3(256), 0, stream>>>(x, mem, xb, mb, n);
  cvt_w_t<<<dim3(3072), dim3(256), 0, stream>>>(Wq,Wk,Wv,Wo,W1,W2, WqT,WkT,WvT,WoT,W1T,W2T);

  int mt = (total + 127)/128;
  gemm_qkv<<<dim3(12, mt), 256, 0, stream>>>(xb, mb, WqT, WkT, WvT, Qb, Kbf, Vtb, total);

  attn_kernel<<<dim3((unsigned)((total + 127)/128), 8, 8), 512, 0, stream>>>(Qb, Kbf, Vtb, attnb, meta, total);

  gemm_bt<<<dim3(4, mt), 256, 0, stream>>>(attnb, WoT, woout, nullptr, total, 512, 512, 1.f, 0, 0);
  ln_fuse<<<dim3((unsigned)((total + 3)/4)), 256, 0, stream>>>(x, nullptr, woout, g1, be1, hb, nullptr, total);

  gemm_bt<<<dim3(16, mt), 256, 0, stream>>>(hb,   W1T, ffn1, b1, total, 2048, 512,  1.f, 1, 0);
  gemm_bt<<<dim3(4,  mt), 256, 0, stream>>>(ffn1, W2T, ffn2, b2, total, 512,  2048, 1.f, 0, 0);
  ln_fuse<<<dim3((unsigned)((total + 3)/4)), 256, 0, stream>>>(nullptr, hb, ffn2, g2, be2, nullptr, out, total);
}

// Round 3
// 184.397 us; speedup vs baseline: 1.3050x; 1.1092x over previous
//
#include <hip/hip_runtime.h>
#include <stdint.h>

typedef short bf8v __attribute__((ext_vector_type(8)));
typedef float f4v  __attribute__((ext_vector_type(4)));
typedef short s8v  __attribute__((ext_vector_type(8)));

__device__ __forceinline__ float bf2f(short b){
  unsigned u = ((unsigned)(unsigned short)b) << 16;
  union { unsigned u; float f; } c; c.u = u; return c.f;
}
__device__ __forceinline__ short f2bf(float f){
  union { float f; unsigned u; } c; c.f = f;
  unsigned r = (c.u + 0x7FFFu + ((c.u >> 16) & 1u)) >> 16;
  return (short)r;
}
__device__ __forceinline__ void gload16(const short* g, short* l){
  __builtin_amdgcn_global_load_lds(
      (const __attribute__((address_space(1))) void*)g,
      (__attribute__((address_space(3))) void*)l, 16, 0, 0);
}

// ---------------- prep: lengths -> offsets (int32/int64 autodetect) ----------
__global__ void prep_kernel(const int* lx, const int* lm, int* meta){
  if (threadIdx.x != 0) return;
  int is64 = ((lx[1] | lx[3] | lx[5] | lx[7]) == 0) ? 1 : 0;
  int ox = 0, om = 0;
  for (int b = 0; b < 8; ++b){
    int a = is64 ? lx[2*b] : lx[b];
    int c = is64 ? lm[2*b] : lm[b];
    meta[b] = a; meta[8+b] = c;
    meta[16+b] = ox; meta[25+b] = om;
    ox += a; om += c;
  }
  meta[24] = ox; meta[33] = om;
}

// ---------------- f32 -> bf16 conversion for x and mem -----------------------
__global__ __launch_bounds__(256) void cvt2bf(const float* __restrict__ x,
                                              const float* __restrict__ mem,
                                              short* __restrict__ xb,
                                              short* __restrict__ mb,
                                              long long n){
  long long t = (long long)blockIdx.x * 256 + threadIdx.x;
  long long i = t * 8;
  const float* s; short* d;
  if (i < n){ s = x + i; d = xb + i; }
  else {
    i -= n; if (i >= n) return;
    s = mem + i; d = mb + i;
  }
  float4 f0 = *(const float4*)s;
  float4 f1 = *(const float4*)(s + 4);
  s8v o;
  o[0]=f2bf(f0.x); o[1]=f2bf(f0.y); o[2]=f2bf(f0.z); o[3]=f2bf(f0.w);
  o[4]=f2bf(f1.x); o[5]=f2bf(f1.y); o[6]=f2bf(f1.z); o[7]=f2bf(f1.w);
  *(s8v*)d = o;
}

// ---------------- weight transpose + convert: W[K][N] -> WT[N][K] bf16 -------
__global__ __launch_bounds__(256) void cvt_w_t(
    const float* __restrict__ Wq, const float* __restrict__ Wk,
    const float* __restrict__ Wv, const float* __restrict__ Wo,
    const float* __restrict__ W1, const float* __restrict__ W2,
    short* __restrict__ WqT, short* __restrict__ WkT,
    short* __restrict__ WvT, short* __restrict__ WoT,
    short* __restrict__ W1T, short* __restrict__ W2T){
  __shared__ float tile[32][33];
  int bid = blockIdx.x;
  const float* W; short* WT; int K, N, t0;
  if      (bid <  256){ W=Wq; WT=WqT; K=512;  N=512;  t0=0;    }
  else if (bid <  512){ W=Wk; WT=WkT; K=512;  N=512;  t0=256;  }
  else if (bid <  768){ W=Wv; WT=WvT; K=512;  N=512;  t0=512;  }
  else if (bid < 1024){ W=Wo; WT=WoT; K=512;  N=512;  t0=768;  }
  else if (bid < 2048){ W=W1; WT=W1T; K=512;  N=2048; t0=1024; }
  else                { W=W2; WT=W2T; K=2048; N=512;  t0=2048; }
  int lt = bid - t0;
  int ntn = N / 32;
  int tk = lt / ntn, tn = lt % ntn;
  int r0 = threadIdx.x >> 5, c = threadIdx.x & 31;
  #pragma unroll
  for (int i = 0; i < 4; ++i){
    int r = r0 + i*8;
    tile[r][c] = W[(long)(tk*32 + r)*N + tn*32 + c];
  }
  __syncthreads();
  #pragma unroll
  for (int i = 0; i < 4; ++i){
    int r = r0 + i*8;
    WT[(long)(tn*32 + r)*K + tk*32 + c] = f2bf(tile[c][r]);
  }
}

// ---------------- generic bf16 MFMA GEMM core: C[M,N] = A[M,K] @ Bt[N,K]^T ---
// BM x 128 tile (BM = 128 or 64), BK=32, 4 waves, double-buffered
// global_load_lds staging with early issue, pre-swizzled source.
template<int BM>
__device__ __forceinline__ void stage_gemm(const short* A, const short* Bt,
    long brow, long bcol, int M, int N, int K, int t,
    short* Als, short* Bls){
  int tid = threadIdx.x;
  #pragma unroll
  for (int i = 0; i < BM/64; ++i){
    int cc = i*256 + tid;
    int row = cc >> 2, slot = cc & 3;
    int cg = slot ^ ((row >> 1) & 3);
    long ar = brow + row; if (ar >= M) ar = M - 1;
    gload16(A + ar*(long)K + t + cg*8, &Als[cc*8]);
  }
  #pragma unroll
  for (int i = 0; i < 2; ++i){
    int cc = i*256 + tid;
    int row = cc >> 2, slot = cc & 3;
    int cg = slot ^ ((row >> 1) & 3);
    long br = bcol + row; if (br >= N) br = N - 1;
    gload16(Bt + br*(long)K + t + cg*8, &Bls[cc*8]);
  }
}

template<int BM>
__device__ __forceinline__ void gemm_core(const short* A, const short* Bt,
    short* __restrict__ C, const float* __restrict__ bias,
    int M, int N, int K, float scale, int relu, int colmajor,
    long brow, long bcol, short* Als, short* Bls){
  constexpr int NREP = (BM == 128) ? 4 : 2;
  int tid = threadIdx.x;
  int lane = tid & 63, w = tid >> 6;
  int wrow = (BM == 128) ? (w >> 1) * 64 : 0;
  int wcol = (BM == 128) ? (w & 1) * 64 : w * 32;
  int l15 = lane & 15, l4 = lane >> 4;

  f4v acc[4][NREP];
  #pragma unroll
  for (int m = 0; m < 4; ++m)
    #pragma unroll
    for (int n = 0; n < NREP; ++n) acc[m][n] = (f4v){0.f,0.f,0.f,0.f};

  int nt = K / 32;
  stage_gemm<BM>(A, Bt, brow, bcol, M, N, K, 0, Als, Bls);
  for (int t = 0; t < nt; ++t){
    __syncthreads();             // buf[t&1] ready, buf[nxt] free
    if (t + 1 < nt)
      stage_gemm<BM>(A, Bt, brow, bcol, M, N, K, (t+1)*32,
                     Als + ((t+1)&1)*(BM*32), Bls + ((t+1)&1)*4096);
    const short* Ab = Als + (t&1)*(BM*32);
    const short* Bb = Bls + (t&1)*4096;
    bf8v a[4], b[NREP];
    #pragma unroll
    for (int m = 0; m < 4; ++m){
      int row = wrow + m*16 + l15;
      int slot = l4 ^ ((row >> 1) & 3);
      a[m] = *(const bf8v*)&Ab[row*32 + slot*8];
    }
    #pragma unroll
    for (int n = 0; n < NREP; ++n){
      int row = wcol + n*16 + l15;
      int slot = l4 ^ ((row >> 1) & 3);
      b[n] = *(const bf8v*)&Bb[row*32 + slot*8];
    }
    #pragma unroll
    for (int m = 0; m < 4; ++m)
      #pragma unroll
      for (int n = 0; n < NREP; ++n)
        acc[m][n] = __builtin_amdgcn_mfma_f32_16x16x32_bf16(a[m], b[n], acc[m][n], 0, 0, 0);
  }

  #pragma unroll
  for (int m = 0; m < 4; ++m){
    #pragma unroll
    for (int n = 0; n < NREP; ++n){
      long col = bcol + wcol + n*16 + l15;
      float bi = (bias != nullptr && col < N) ? bias[col] : 0.f;
      #pragma unroll
      for (int j = 0; j < 4; ++j){
        long row = brow + wrow + m*16 + 4*l4 + j;
        if (row < M && col < N){
          float v = acc[m][n][j] * scale + bi;
          if (relu) v = fmaxf(v, 0.f);
          C[colmajor ? (col*(long)M + row) : (row*(long)N + col)] = f2bf(v);
        }
      }
    }
  }
}

__global__ __launch_bounds__(256) void gemm_bt(
    const short* __restrict__ A, const short* __restrict__ Bt,
    short* __restrict__ C, const float* __restrict__ bias,
    int M, int N, int K, float scale, int relu, int colmajor){
  __shared__ __align__(16) short Als[2*128*32];
  __shared__ __align__(16) short Bls[2*128*32];
  gemm_core<128>(A, Bt, C, bias, M, N, K, scale, relu, colmajor,
                 (long)blockIdx.y * 128, (long)blockIdx.x * 128, Als, Bls);
}

__global__ __launch_bounds__(256) void gemm_bt64(
    const short* __restrict__ A, const short* __restrict__ Bt,
    short* __restrict__ C, const float* __restrict__ bias,
    int M, int N, int K, float scale, int relu, int colmajor){
  __shared__ __align__(16) short Als[2*64*32];
  __shared__ __align__(16) short Bls[2*128*32];
  gemm_core<64>(A, Bt, C, bias, M, N, K, scale, relu, colmajor,
                (long)blockIdx.y * 64, (long)blockIdx.x * 128, Als, Bls);
}

// fused QKV (BM=64): grid.x = 12 (4 col-tiles x {Q,K,V}); Q from xb, K/V from mb.
__global__ __launch_bounds__(256) void gemm_qkv(
    const short* __restrict__ xb, const short* __restrict__ mb,
    const short* __restrict__ WqT, const short* __restrict__ WkT,
    const short* __restrict__ WvT,
    short* __restrict__ Qb, short* __restrict__ Kbf, short* __restrict__ Vtb,
    int total){
  __shared__ __align__(16) short Als[2*64*32];
  __shared__ __align__(16) short Bls[2*128*32];
  int seg = blockIdx.x >> 2;
  const short* A  = (seg == 0) ? xb : mb;
  const short* Bt = (seg == 0) ? WqT : ((seg == 1) ? WkT : WvT);
  short* C        = (seg == 0) ? Qb  : ((seg == 1) ? Kbf : Vtb);
  float scale     = (seg == 0) ? 0.125f : 1.f;
  int colmajor    = (seg == 2);
  gemm_core<64>(A, Bt, C, nullptr, total, 512, 512, scale, 0, colmajor,
                (long)blockIdx.y * 64, (long)(blockIdx.x & 3) * 128, Als, Bls);
}

// ---------------- flash attention over packed batches ------------------------
// block = (qtile of 128, head, batch); 8 waves x 16 q-rows; kv tiles of 64.
// 3-buffer ring, counted vmcnt(2) (never drain mid-loop), raw s_barrier.
__global__ __launch_bounds__(512) void attn_kernel(
    const short* __restrict__ Q, const short* __restrict__ Kb,
    const short* __restrict__ Vt, short* __restrict__ Ob,
    const int* __restrict__ meta, int total){
  int qt = blockIdx.x, h = blockIdx.y, b = blockIdx.z;
  int Lx = meta[b], Lm = meta[8+b];
  int ox = meta[16+b], om = meta[25+b];
  if (qt*128 >= Lx) return;

  __shared__ __align__(16) short Kls[3][64*64];
  __shared__ __align__(16) short Vls[3][64*64];
  __shared__ __align__(16) short Pls[8][16*64];

  int tid = threadIdx.x;
  int lane = tid & 63, w = tid >> 6;
  int l15 = lane & 15, l4 = lane >> 4;

  // Q fragments (1/sqrt(dh) pre-folded into Q by the QKV GEMM).
  bf8v aq0, aq1;
  {
    int qrow = qt*128 + w*16 + l15;
    int grow = ox + (qrow < Lx ? qrow : Lx - 1);
    const short* qp = Q + (long)grow*512 + h*64 + l4*8;
    aq0 = *(const bf8v*)qp;
    aq1 = *(const bf8v*)(qp + 32);
  }
  float mrun[4] = {-1e30f,-1e30f,-1e30f,-1e30f};
  float lrun[4] = {0.f,0.f,0.f,0.f};
  f4v o[4];
  #pragma unroll
  for (int n = 0; n < 4; ++n) o[n] = (f4v){0.f,0.f,0.f,0.f};

  int nt = (Lm + 63) / 64;

  // each of 512 threads loads one 16B K chunk + one 16B V chunk per stage
  #define ATTN_STAGE(T, BUF)                                                   \
    {                                                                          \
      int c = tid;                                                             \
      int rr = c >> 3, slot = c & 7;                                           \
      int ch = slot ^ (rr & 7);                                                \
      int kv0_ = (T) * 64;                                                     \
      int tok = kv0_ + rr; if (tok >= Lm) tok = Lm - 1;                        \
      gload16(Kb + (long)(om + tok)*512 + h*64 + ch*8, &Kls[BUF][c*8]);        \
      int kvs = kv0_ + ch*8; if (kvs + 8 > Lm) kvs = Lm - 8;                   \
      gload16(Vt + (long)(h*64 + rr)*total + om + kvs, &Vls[BUF][c*8]);        \
    }

  ATTN_STAGE(0, 0)
  if (1 < nt) ATTN_STAGE(1, 1)

  int buf = 0;
  for (int t = 0; t < nt; ++t){
    // wait for stage(t): it is the oldest of (at most) stages {t, t+1} in
    // flight; each stage = 2 loads/thread; vmcnt retires in issue order.
    if (t + 1 < nt) asm volatile("s_waitcnt vmcnt(2)" ::: "memory");
    else            asm volatile("s_waitcnt vmcnt(0)" ::: "memory");
    __builtin_amdgcn_s_barrier();
    asm volatile("" ::: "memory");   // no LDS read hoists above the barrier
    if (t + 2 < nt){
      int bs = buf + 2; if (bs >= 3) bs -= 3;   // == (t+2)%3; all waves are
      ATTN_STAGE(t+2, bs)                       // past compute(t-1) -> free
    }
    int kv0 = t * 64;

    // S = Q K^T  (per wave: 16q x 64kv)
    f4v s[4];
    #pragma unroll
    for (int n = 0; n < 4; ++n){
      int kvrow = n*16 + l15;
      int sl0 = l4 ^ (kvrow & 7);
      int sl1 = (4 + l4) ^ (kvrow & 7);
      bf8v b0 = *(const bf8v*)&Kls[buf][kvrow*64 + sl0*8];
      bf8v b1 = *(const bf8v*)&Kls[buf][kvrow*64 + sl1*8];
      f4v z = (f4v){0.f,0.f,0.f,0.f};
      z = __builtin_amdgcn_mfma_f32_16x16x32_bf16(aq0, b0, z, 0, 0, 0);
      z = __builtin_amdgcn_mfma_f32_16x16x32_bf16(aq1, b1, z, 0, 0, 0);
      s[n] = z;
    }
    // mask invalid kv columns
    #pragma unroll
    for (int n = 0; n < 4; ++n){
      if (kv0 + n*16 + l15 >= Lm){
        s[n][0] = -1e30f; s[n][1] = -1e30f; s[n][2] = -1e30f; s[n][3] = -1e30f;
      }
    }
    // online softmax (row = 4*l4 + j, 16 lanes per row share via shfl_xor)
    #pragma unroll
    for (int j = 0; j < 4; ++j){
      float m1 = fmaxf(fmaxf(s[0][j], s[1][j]), fmaxf(s[2][j], s[3][j]));
      m1 = fmaxf(m1, __shfl_xor(m1, 1, 64));
      m1 = fmaxf(m1, __shfl_xor(m1, 2, 64));
      m1 = fmaxf(m1, __shfl_xor(m1, 4, 64));
      m1 = fmaxf(m1, __shfl_xor(m1, 8, 64));
      float mnew = fmaxf(mrun[j], m1);
      float sc = __expf(mrun[j] - mnew);
      float rs = 0.f;
      #pragma unroll
      for (int n = 0; n < 4; ++n){
        float p = __expf(s[n][j] - mnew);
        s[n][j] = p; rs += p;
      }
      rs += __shfl_xor(rs, 1, 64); rs += __shfl_xor(rs, 2, 64);
      rs += __shfl_xor(rs, 4, 64); rs += __shfl_xor(rs, 8, 64);
      lrun[j] = lrun[j] * sc + rs;
      mrun[j] = mnew;
      o[0][j] *= sc; o[1][j] *= sc; o[2][j] *= sc; o[3][j] *= sc;
    }
    // P -> wave-private LDS (bf16, swizzled) to re-fragment for PV
    #pragma unroll
    for (int n = 0; n < 4; ++n){
      int pcol = n*16 + l15;
      #pragma unroll
      for (int j = 0; j < 4; ++j){
        int prow = 4*l4 + j;
        Pls[w][prow*64 + (((pcol >> 3) ^ (prow & 7)) << 3) + (pcol & 7)] = f2bf(s[n][j]);
      }
    }
    // O += P @ V
    #pragma unroll
    for (int ks = 0; ks < 2; ++ks){
      int ch = ks*4 + l4;
      bf8v ap = *(const bf8v*)&Pls[w][l15*64 + ((ch ^ (l15 & 7)) << 3)];
      #pragma unroll
      for (int n = 0; n < 4; ++n){
        int d = n*16 + l15;
        bf8v bv = *(const bf8v*)&Vls[buf][d*64 + ((ch ^ (d & 7)) << 3)];
        o[n] = __builtin_amdgcn_mfma_f32_16x16x32_bf16(ap, bv, o[n], 0, 0, 0);
      }
    }
    buf = (buf + 1 == 3) ? 0 : buf + 1;
  }
  #undef ATTN_STAGE

  #pragma unroll
  for (int n = 0; n < 4; ++n){
    #pragma unroll
    for (int j = 0; j < 4; ++j){
      int qrow = qt*128 + w*16 + 4*l4 + j;
      if (qrow < Lx){
        float val = o[n][j] / lrun[j];
        Ob[(long)(ox + qrow)*512 + h*64 + n*16 + l15] = f2bf(val);
      }
    }
  }
}

// ---------------- fused residual + LayerNorm (wave per 512-col row) ----------
__global__ __launch_bounds__(256) void ln_fuse(
    const float* __restrict__ Af, const short* __restrict__ Ab,
    const short* __restrict__ Bb,
    const float* __restrict__ gamma, const float* __restrict__ beta,
    short* __restrict__ outb, float* __restrict__ outf, int rows){
  int w = threadIdx.x >> 6, lane = threadIdx.x & 63;
  long row = (long)blockIdx.x * 4 + w;
  if (row >= rows) return;
  int c0 = lane * 8;
  long base = row * 512 + c0;
  float v[8];
  if (Af){
    float4 f0 = *(const float4*)(Af + base);
    float4 f1 = *(const float4*)(Af + base + 4);
    v[0]=f0.x; v[1]=f0.y; v[2]=f0.z; v[3]=f0.w;
    v[4]=f1.x; v[5]=f1.y; v[6]=f1.z; v[7]=f1.w;
  } else {
    s8v a = *(const s8v*)(Ab + base);
    #pragma unroll
    for (int j = 0; j < 8; ++j) v[j] = bf2f(a[j]);
  }
  s8v bb = *(const s8v*)(Bb + base);
  #pragma unroll
  for (int j = 0; j < 8; ++j) v[j] += bf2f(bb[j]);
  float sum = 0.f;
  #pragma unroll
  for (int j = 0; j < 8; ++j) sum += v[j];
  #pragma unroll
  for (int m = 1; m < 64; m <<= 1) sum += __shfl_xor(sum, m, 64);
  float mu = sum * (1.f/512.f);
  float q = 0.f;
  #pragma unroll
  for (int j = 0; j < 8; ++j){ float d = v[j] - mu; q += d*d; }
  #pragma unroll
  for (int m = 1; m < 64; m <<= 1) q += __shfl_xor(q, m, 64);
  float rs = rsqrtf(q * (1.f/512.f) + 1e-6f);
  float ov[8];
  #pragma unroll
  for (int j = 0; j < 8; ++j)
    ov[j] = (v[j] - mu) * rs * gamma[c0 + j] + beta[c0 + j];
  if (outb){
    s8v os;
    #pragma unroll
    for (int j = 0; j < 8; ++j) os[j] = f2bf(ov[j]);
    *(s8v*)(outb + base) = os;
  } else {
    float4 f0 = {ov[0], ov[1], ov[2], ov[3]};
    float4 f1 = {ov[4], ov[5], ov[6], ov[7]};
    *(float4*)(outf + base) = f0;
    *(float4*)(outf + base + 4) = f1;
  }
}

// ---------------- host ------------------------------------------------------
extern "C" void kernel_launch(void* const* d_in, const int* in_sizes, int n_in,
                              void* d_out, int out_size, void* d_ws, size_t ws_size,
                              hipStream_t stream){
  (void)n_in; (void)out_size; (void)ws_size;
  const float* x   = (const float*)d_in[0];
  const float* mem = (const float*)d_in[1];
  const int*   lxr = (const int*)d_in[2];
  const int*   lmr = (const int*)d_in[3];
  const float* Wq  = (const float*)d_in[4];
  const float* Wk  = (const float*)d_in[5];
  const float* Wv  = (const float*)d_in[6];
  const float* Wo  = (const float*)d_in[7];
  const float* g1  = (const float*)d_in[8];
  const float* be1 = (const float*)d_in[9];
  const float* W1  = (const float*)d_in[10];
  const float* b1  = (const float*)d_in[11];
  const float* W2  = (const float*)d_in[12];
  const float* b2  = (const float*)d_in[13];
  const float* g2  = (const float*)d_in[14];
  const float* be2 = (const float*)d_in[15];
  float* out = (float*)d_out;

  int total = in_sizes[0] / 512;
  if (total <= 0) return;
  long long n = (long long)total * 512;

  char* p = (char*)d_ws;
  int*   meta = (int*)p;    p += 256;
  short* xb   = (short*)p;  p += n*2;
  short* mb   = (short*)p;  p += n*2;
  short* Qb   = (short*)p;  p += n*2;
  short* Kbf  = (short*)p;  p += n*2;
  short* Vtb  = (short*)p;  p += n*2;
  short* attnb= (short*)p;  p += n*2;
  short* woout= (short*)p;  p += n*2;
  short* hb   = (short*)p;  p += n*2;
  short* ffn1 = (short*)p;  p += (long long)total*2048*2;
  short* ffn2 = (short*)p;  p += n*2;
  short* WqT  = (short*)p;  p += 512*512*2;
  short* WkT  = (short*)p;  p += 512*512*2;
  short* WvT  = (short*)p;  p += 512*512*2;
  short* WoT  = (short*)p;  p += 512*512*2;
  short* W1T  = (short*)p;  p += 2048*512*2;
  short* W2T  = (short*)p;  p += 512*2048*2;

  prep_kernel<<<1, 64, 0, stream>>>(lxr, lmr, meta);

  long long th = (2*n)/8;
  cvt2bf<<<dim3((unsigned)((th + 255)/256)), dim3(256), 0, stream>>>(x, mem, xb, mb, n);
  cvt_w_t<<<dim3(3072), dim3(256), 0, stream>>>(Wq,Wk,Wv,Wo,W1,W2, WqT,WkT,WvT,WoT,W1T,W2T);

  int mt128 = (total + 127)/128;
  int mt64  = (total + 63)/64;
  gemm_qkv<<<dim3(12, mt64), 256, 0, stream>>>(xb, mb, WqT, WkT, WvT, Qb, Kbf, Vtb, total);

  attn_kernel<<<dim3((unsigned)((total + 127)/128), 8, 8), 512, 0, stream>>>(Qb, Kbf, Vtb, attnb, meta, total);

  gemm_bt64<<<dim3(4, mt64), 256, 0, stream>>>(attnb, WoT, woout, nullptr, total, 512, 512, 1.f, 0, 0);
  ln_fuse<<<dim3((unsigned)((total + 3)/4)), 256, 0, stream>>>(x, nullptr, woout, g1, be1, hb, nullptr, total);

  gemm_bt<<<dim3(16, mt128), 256, 0, stream>>>(hb,   W1T, ffn1, b1, total, 2048, 512,  1.f, 1, 0);
  gemm_bt64<<<dim3(4, mt64), 256, 0, stream>>>(ffn1, W2T, ffn2, b2, total, 512,  2048, 1.f, 0, 0);
  ln_fuse<<<dim3((unsigned)((total + 3)/4)), 256, 0, stream>>>(nullptr, hb, ffn2, g2, be2, nullptr, out, total);
}